// Round 1
// baseline (669.761 us; speedup 1.0000x reference)
//
#include <hip/hip_runtime.h>
#include <math.h>

#define NN 50000
#define HID 128
#define NG 64
#define BN_EPS 1e-5f

// ---------------- degree / CSR build ----------------

__global__ __launch_bounds__(256) void k_count_deg(const int* __restrict__ dst,
                                                   int* __restrict__ ideg, int E) {
    int e = blockIdx.x * 256 + threadIdx.x;
    if (e < E) atomicAdd(&ideg[dst[e]], 1);
}

__global__ __launch_bounds__(256) void k_dis(const int* __restrict__ ideg,
                                             float* __restrict__ dis, int n) {
    int i = blockIdx.x * 256 + threadIdx.x;
    if (i < n) dis[i] = rsqrtf((float)(ideg[i] + 1));  // +1 self-loop; deg>0 always
}

__global__ __launch_bounds__(256) void k_scan_a(const int* __restrict__ ideg,
                                                int* __restrict__ bsum, int n) {
    __shared__ int s[256];
    int t = threadIdx.x;
    int i = blockIdx.x * 256 + t;
    s[t] = (i < n) ? ideg[i] : 0;
    __syncthreads();
    for (int off = 128; off > 0; off >>= 1) {
        if (t < off) s[t] += s[t + off];
        __syncthreads();
    }
    if (t == 0) bsum[blockIdx.x] = s[0];
}

// single block: exclusive scan of nb (<=256) block sums, also writes row_ptr[n]=E
__global__ __launch_bounds__(256) void k_scan_b(int* __restrict__ bsum, int nb,
                                                int* __restrict__ row_ptr, int n, int E) {
    __shared__ int s[256];
    int t = threadIdx.x;
    s[t] = (t < nb) ? bsum[t] : 0;
    __syncthreads();
    for (int off = 1; off < 256; off <<= 1) {
        int v = (t >= off) ? s[t - off] : 0;
        __syncthreads();
        s[t] += v;
        __syncthreads();
    }
    int ex = (t == 0) ? 0 : s[t - 1];
    if (t < nb) bsum[t] = ex;
    if (t == 0) row_ptr[n] = E;
}

__global__ __launch_bounds__(256) void k_scan_c(const int* __restrict__ ideg,
                                                const int* __restrict__ boff,
                                                int* __restrict__ row_ptr,
                                                int* __restrict__ cursor, int n) {
    __shared__ int s[256];
    int t = threadIdx.x;
    int i = blockIdx.x * 256 + t;
    int v = (i < n) ? ideg[i] : 0;
    s[t] = v;
    __syncthreads();
    for (int off = 1; off < 256; off <<= 1) {
        int u = (t >= off) ? s[t - off] : 0;
        __syncthreads();
        s[t] += u;
        __syncthreads();
    }
    int excl = s[t] - v;
    int base = boff[blockIdx.x];
    if (i < n) {
        row_ptr[i] = base + excl;
        cursor[i]  = base + excl;
    }
}

__global__ __launch_bounds__(256) void k_fill_csr(const int* __restrict__ src,
                                                  const int* __restrict__ dst,
                                                  int* __restrict__ cursor,
                                                  int* __restrict__ col_idx, int E) {
    int e = blockIdx.x * 256 + threadIdx.x;
    if (e < E) {
        int d = dst[e];
        int pos = atomicAdd(&cursor[d], 1);
        col_idx[pos] = src[e];
    }
}

// ---------------- GEMM: out[row][c] = dis[row] * sum_k in[row][k]*W[k][c] ----------------
// block = 256 threads, 32 rows per block, thread computes 4 rows x 4 cols.

__global__ __launch_bounds__(256) void k_gemm_scale(const float* __restrict__ in,
                                                    const float* __restrict__ W,
                                                    const float* __restrict__ dis,
                                                    float* __restrict__ out, int n) {
    __shared__ float Ws[64][128];   // 32 KB, K-half of W
    __shared__ float xs[32][132];   // 16.9 KB, 32 rows full-K (pad 132 to spread banks)
    int t = threadIdx.x;
    int row0 = blockIdx.x * 32;
    int r4 = (t >> 5) * 4;          // row offset 0..28
    int c4 = (t & 31) * 4;          // col offset 0..124

    // stage x rows (full K), coalesced float4
    #pragma unroll
    for (int i = 0; i < 4; ++i) {
        int idx = t + i * 256;          // 0..1023 float4s
        int xr = idx >> 5;              // 0..31
        int xc = (idx & 31) << 2;       // 0..124
        int grow = row0 + xr;
        float4 v = make_float4(0.f, 0.f, 0.f, 0.f);
        if (grow < n) v = *(const float4*)&in[(size_t)grow * 128 + xc];
        *(float4*)&xs[xr][xc] = v;
    }

    float acc[4][4] = {};
    for (int kk = 0; kk < 128; kk += 64) {
        __syncthreads();   // xs staged / previous compute done before Ws overwrite
        #pragma unroll
        for (int i = 0; i < 8; ++i) {
            int idx = t + i * 256;      // 0..2047 float4s
            int wr = idx >> 5;          // 0..63
            int wc = (idx & 31) << 2;
            *(float4*)&Ws[wr][wc] = *(const float4*)&W[(size_t)(kk + wr) * 128 + wc];
        }
        __syncthreads();
        for (int k = 0; k < 64; k += 4) {
            float4 xv0 = *(const float4*)&xs[r4 + 0][kk + k];
            float4 xv1 = *(const float4*)&xs[r4 + 1][kk + k];
            float4 xv2 = *(const float4*)&xs[r4 + 2][kk + k];
            float4 xv3 = *(const float4*)&xs[r4 + 3][kk + k];
            const float* xp0 = (const float*)&xv0;
            const float* xp1 = (const float*)&xv1;
            const float* xp2 = (const float*)&xv2;
            const float* xp3 = (const float*)&xv3;
            #pragma unroll
            for (int j = 0; j < 4; ++j) {
                float4 wv = *(const float4*)&Ws[k + j][c4];
                acc[0][0] = fmaf(xp0[j], wv.x, acc[0][0]);
                acc[0][1] = fmaf(xp0[j], wv.y, acc[0][1]);
                acc[0][2] = fmaf(xp0[j], wv.z, acc[0][2]);
                acc[0][3] = fmaf(xp0[j], wv.w, acc[0][3]);
                acc[1][0] = fmaf(xp1[j], wv.x, acc[1][0]);
                acc[1][1] = fmaf(xp1[j], wv.y, acc[1][1]);
                acc[1][2] = fmaf(xp1[j], wv.z, acc[1][2]);
                acc[1][3] = fmaf(xp1[j], wv.w, acc[1][3]);
                acc[2][0] = fmaf(xp2[j], wv.x, acc[2][0]);
                acc[2][1] = fmaf(xp2[j], wv.y, acc[2][1]);
                acc[2][2] = fmaf(xp2[j], wv.z, acc[2][2]);
                acc[2][3] = fmaf(xp2[j], wv.w, acc[2][3]);
                acc[3][0] = fmaf(xp3[j], wv.x, acc[3][0]);
                acc[3][1] = fmaf(xp3[j], wv.y, acc[3][1]);
                acc[3][2] = fmaf(xp3[j], wv.z, acc[3][2]);
                acc[3][3] = fmaf(xp3[j], wv.w, acc[3][3]);
            }
        }
    }
    #pragma unroll
    for (int i = 0; i < 4; ++i) {
        int grow = row0 + r4 + i;
        if (grow < n) {
            float ds = dis[grow];
            float4 o = make_float4(acc[i][0] * ds, acc[i][1] * ds,
                                   acc[i][2] * ds, acc[i][3] * ds);
            *(float4*)&out[(size_t)grow * 128 + c4] = o;
        }
    }
}

// ---------------- aggregation + bias + BN + ReLU ----------------
// one wave per node; lanes hold 2 features each (float2)

__global__ __launch_bounds__(256) void k_agg_bn_relu(const float* __restrict__ hws,
                                                     const int* __restrict__ row_ptr,
                                                     const int* __restrict__ col_idx,
                                                     const float* __restrict__ dis,
                                                     const float* __restrict__ bias,
                                                     const float* __restrict__ gamma,
                                                     const float* __restrict__ beta,
                                                     const float* __restrict__ mean,
                                                     const float* __restrict__ var,
                                                     float* __restrict__ out, int n) {
    int wave = threadIdx.x >> 6;
    int lane = threadIdx.x & 63;
    int d = blockIdx.x * 4 + wave;
    if (d >= n) return;
    int e0 = row_ptr[d];
    int e1 = row_ptr[d + 1];
    const float2* base = (const float2*)hws;   // element s*64+lane == hws[s][2*lane..]
    float2 acc = make_float2(0.f, 0.f);
    int e = e0;
    for (; e + 4 <= e1; e += 4) {
        int s0 = col_idx[e + 0];
        int s1 = col_idx[e + 1];
        int s2 = col_idx[e + 2];
        int s3 = col_idx[e + 3];
        float2 v0 = base[(size_t)s0 * 64 + lane];
        float2 v1 = base[(size_t)s1 * 64 + lane];
        float2 v2 = base[(size_t)s2 * 64 + lane];
        float2 v3 = base[(size_t)s3 * 64 + lane];
        acc.x += v0.x + v1.x + v2.x + v3.x;
        acc.y += v0.y + v1.y + v2.y + v3.y;
    }
    for (; e < e1; ++e) {
        int s = col_idx[e];
        float2 v = base[(size_t)s * 64 + lane];
        acc.x += v.x;
        acc.y += v.y;
    }
    float2 self = base[(size_t)d * 64 + lane];
    acc.x += self.x;
    acc.y += self.y;
    float dd = dis[d];
    int f = lane * 2;
    float2 bv = *(const float2*)&bias[f];
    float2 gm = *(const float2*)&gamma[f];
    float2 bt = *(const float2*)&beta[f];
    float2 mn = *(const float2*)&mean[f];
    float2 vr = *(const float2*)&var[f];
    float vx = acc.x * dd + bv.x;
    float vy = acc.y * dd + bv.y;
    float sx = gm.x * rsqrtf(vr.x + BN_EPS);
    float sy = gm.y * rsqrtf(vr.y + BN_EPS);
    float rx = fmaxf((vx - mn.x) * sx + bt.x, 0.f);
    float ry = fmaxf((vy - mn.y) * sy + bt.y, 0.f);
    *(float2*)&out[(size_t)d * 128 + f] = make_float2(rx, ry);
}

// ---------------- attention + segment pooling ----------------
// block handles 256 consecutive rows; batch is SORTED.

__global__ __launch_bounds__(256) void k_att_pool(const float* __restrict__ h2,
                                                  const int* __restrict__ batch,
                                                  const float* __restrict__ att_w,
                                                  float* __restrict__ att_out,
                                                  float* __restrict__ gpool, int n) {
    __shared__ float sh_att[256];
    int chunk = blockIdx.x * 256;
    int wave = threadIdx.x >> 6;
    int lane = threadIdx.x & 63;
    float2 aw = *(const float2*)&att_w[lane * 2];
    // phase 1: per-row attention (wave per row, 64 rows per wave)
    for (int rr = 0; rr < 64; ++rr) {
        int local = wave * 64 + rr;
        int row = chunk + local;
        if (row < n) {
            float2 v = *(const float2*)&h2[(size_t)row * 128 + lane * 2];
            float p = v.x * aw.x + v.y * aw.y;
            #pragma unroll
            for (int off = 32; off > 0; off >>= 1) p += __shfl_down(p, off);
            if (lane == 0) {
                float a = 1.f / (1.f + expf(-p));
                att_out[row] = a;
                sh_att[local] = a;
            }
        }
    }
    __syncthreads();
    // phase 2: run-length pooled accumulation, 1 atomic per segment boundary
    int f = threadIdx.x & 127;
    int half = threadIdx.x >> 7;
    int r0 = half * 128, r1 = r0 + 128;
    float acc = 0.f;
    int cur = -1;
    for (int rr = r0; rr < r1; ++rr) {
        int row = chunk + rr;
        if (row >= n) break;                 // uniform across the half
        int g = batch[row];
        if (g != cur) {
            if (cur >= 0) atomicAdd(&gpool[cur * 128 + f], acc);
            acc = 0.f;
            cur = g;
        }
        acc += h2[(size_t)row * 128 + f] * sh_att[rr];
    }
    if (cur >= 0) atomicAdd(&gpool[cur * 128 + f], acc);
}

__global__ __launch_bounds__(256) void k_logits(const float* __restrict__ gpool,
                                                const float* __restrict__ cls_w,
                                                const float* __restrict__ cls_b,
                                                float* __restrict__ out) {
    int wave = threadIdx.x >> 6;
    int lane = threadIdx.x & 63;
    float2 cw = *(const float2*)&cls_w[lane * 2];
    for (int g = wave; g < NG; g += 4) {
        float2 v = *(const float2*)&gpool[g * 128 + lane * 2];
        float p = v.x * cw.x + v.y * cw.y;
        #pragma unroll
        for (int off = 32; off > 0; off >>= 1) p += __shfl_down(p, off);
        if (lane == 0) out[g] = p + cls_b[0];
    }
}

// ---------------- launch ----------------

extern "C" void kernel_launch(void* const* d_in, const int* in_sizes, int n_in,
                              void* d_out, int out_size, void* d_ws, size_t ws_size,
                              hipStream_t stream) {
    const float* x   = (const float*)d_in[0];
    const int*   ei  = (const int*)d_in[1];     // int32 (JAX x64 disabled)
    const int*   bat = (const int*)d_in[2];
    const float* W1  = (const float*)d_in[3];
    const float* b1  = (const float*)d_in[4];
    const float* g1  = (const float*)d_in[5];
    const float* bt1 = (const float*)d_in[6];
    const float* mn1 = (const float*)d_in[7];
    const float* vr1 = (const float*)d_in[8];
    const float* W2  = (const float*)d_in[9];
    const float* b2  = (const float*)d_in[10];
    const float* g2  = (const float*)d_in[11];
    const float* bt2 = (const float*)d_in[12];
    const float* mn2 = (const float*)d_in[13];
    const float* vr2 = (const float*)d_in[14];
    const float* attw = (const float*)d_in[15];
    const float* clsw = (const float*)d_in[16];
    const float* clsb = (const float*)d_in[17];

    int E = in_sizes[1] / 2;
    int n = in_sizes[2];
    const int* src = ei;
    const int* dst = ei + E;

    // workspace layout (256B-aligned regions), total ~58.5 MB
    char* ws = (char*)d_ws;
    auto alloc = [&](size_t bytes) {
        void* p = (void*)ws;
        ws += (bytes + 255) & ~(size_t)255;
        return p;
    };
    int*   ideg    = (int*)alloc((size_t)n * 4);
    int*   row_ptr = (int*)alloc((size_t)(n + 1) * 4);
    int*   cursor  = (int*)alloc((size_t)n * 4);
    int*   bsum    = (int*)alloc(256 * 4);
    int*   col_idx = (int*)alloc((size_t)E * 4);
    float* dis     = (float*)alloc((size_t)n * 4);
    float* bufA    = (float*)alloc((size_t)n * 128 * 4);
    float* bufB    = (float*)alloc((size_t)n * 128 * 4);
    float* gpool   = (float*)alloc((size_t)NG * 128 * 4);

    hipMemsetAsync(ideg, 0, (size_t)n * 4, stream);
    hipMemsetAsync(gpool, 0, (size_t)NG * 128 * 4, stream);

    int eb  = (E + 255) / 256;
    int nbn = (n + 255) / 256;

    k_count_deg<<<eb, 256, 0, stream>>>(dst, ideg, E);
    k_dis<<<nbn, 256, 0, stream>>>(ideg, dis, n);
    k_scan_a<<<nbn, 256, 0, stream>>>(ideg, bsum, n);
    k_scan_b<<<1, 256, 0, stream>>>(bsum, nbn, row_ptr, n, E);
    k_scan_c<<<nbn, 256, 0, stream>>>(ideg, bsum, row_ptr, cursor, n);
    k_fill_csr<<<eb, 256, 0, stream>>>(src, dst, cursor, col_idx, E);

    int gb = (n + 31) / 32;
    int ab = (n + 3) / 4;
    // conv1: hws1 = (x@W1)*dis -> bufA ; agg+BN+ReLU -> bufB (=h1)
    k_gemm_scale<<<gb, 256, 0, stream>>>(x, W1, dis, bufA, n);
    k_agg_bn_relu<<<ab, 256, 0, stream>>>(bufA, row_ptr, col_idx, dis, b1, g1, bt1, mn1, vr1, bufB, n);
    // conv2: hws2 = (h1@W2)*dis -> bufA ; agg+BN+ReLU -> bufB (=h2)
    k_gemm_scale<<<gb, 256, 0, stream>>>(bufB, W2, dis, bufA, n);
    k_agg_bn_relu<<<ab, 256, 0, stream>>>(bufA, row_ptr, col_idx, dis, b2, g2, bt2, mn2, vr2, bufB, n);

    float* out = (float*)d_out;
    k_att_pool<<<nbn, 256, 0, stream>>>(bufB, bat, attw, out + NG, gpool, n);
    k_logits<<<1, 256, 0, stream>>>(gpool, clsw, clsb, out);
}

// Round 2
// 567.551 us; speedup vs baseline: 1.1801x; 1.1801x over previous
//
#include <hip/hip_runtime.h>
#include <math.h>

#define NN 50000
#define HID 128
#define NG 64
#define BN_EPS 1e-5f

// ---------------- degree+rank / CSR build ----------------
// One atomic pass gives BOTH the degree histogram and each edge's rank
// within its dst row. The later scatter then needs no atomics at all.

__global__ __launch_bounds__(256) void k_rank_deg(const int* __restrict__ dst,
                                                  int* __restrict__ ideg,
                                                  int* __restrict__ pos, int E) {
    int e = blockIdx.x * 256 + threadIdx.x;
    if (e < E) pos[e] = atomicAdd(&ideg[dst[e]], 1);
}

__global__ __launch_bounds__(256) void k_dis(const int* __restrict__ ideg,
                                             float* __restrict__ dis, int n) {
    int i = blockIdx.x * 256 + threadIdx.x;
    if (i < n) dis[i] = rsqrtf((float)(ideg[i] + 1));  // +1 self-loop
}

__global__ __launch_bounds__(256) void k_scan_a(const int* __restrict__ ideg,
                                                int* __restrict__ bsum, int n) {
    __shared__ int s[256];
    int t = threadIdx.x;
    int i = blockIdx.x * 256 + t;
    s[t] = (i < n) ? ideg[i] : 0;
    __syncthreads();
    for (int off = 128; off > 0; off >>= 1) {
        if (t < off) s[t] += s[t + off];
        __syncthreads();
    }
    if (t == 0) bsum[blockIdx.x] = s[0];
}

// single block: exclusive scan of nb (<=256) block sums, also writes row_ptr[n]=E
__global__ __launch_bounds__(256) void k_scan_b(int* __restrict__ bsum, int nb,
                                                int* __restrict__ row_ptr, int n, int E) {
    __shared__ int s[256];
    int t = threadIdx.x;
    s[t] = (t < nb) ? bsum[t] : 0;
    __syncthreads();
    for (int off = 1; off < 256; off <<= 1) {
        int v = (t >= off) ? s[t - off] : 0;
        __syncthreads();
        s[t] += v;
        __syncthreads();
    }
    int ex = (t == 0) ? 0 : s[t - 1];
    if (t < nb) bsum[t] = ex;
    if (t == 0) row_ptr[n] = E;
}

__global__ __launch_bounds__(256) void k_scan_c(const int* __restrict__ ideg,
                                                const int* __restrict__ boff,
                                                int* __restrict__ row_ptr, int n) {
    __shared__ int s[256];
    int t = threadIdx.x;
    int i = blockIdx.x * 256 + t;
    int v = (i < n) ? ideg[i] : 0;
    s[t] = v;
    __syncthreads();
    for (int off = 1; off < 256; off <<= 1) {
        int u = (t >= off) ? s[t - off] : 0;
        __syncthreads();
        s[t] += u;
        __syncthreads();
    }
    int excl = s[t] - v;
    int base = boff[blockIdx.x];
    if (i < n) row_ptr[i] = base + excl;
}

// scatter WITHOUT atomics: position = row_ptr[dst] + precomputed rank
__global__ __launch_bounds__(256) void k_scatter(const int* __restrict__ src,
                                                 const int* __restrict__ dst,
                                                 const int* __restrict__ row_ptr,
                                                 const int* __restrict__ pos,
                                                 int* __restrict__ col_idx, int E) {
    int e = blockIdx.x * 256 + threadIdx.x;
    if (e < E) {
        int d = dst[e];
        col_idx[row_ptr[d] + pos[e]] = src[e];
    }
}

// ---------------- GEMM: out[row][c] = dis[row] * sum_k in[row][k]*W[k][c] ----------------
// block = 256 threads, 32 rows per block, thread computes 4 rows x 4 cols.

__global__ __launch_bounds__(256) void k_gemm_scale(const float* __restrict__ in,
                                                    const float* __restrict__ W,
                                                    const float* __restrict__ dis,
                                                    float* __restrict__ out, int n) {
    __shared__ float Ws[64][128];
    __shared__ float xs[32][132];
    int t = threadIdx.x;
    int row0 = blockIdx.x * 32;
    int r4 = (t >> 5) * 4;
    int c4 = (t & 31) * 4;

    #pragma unroll
    for (int i = 0; i < 4; ++i) {
        int idx = t + i * 256;
        int xr = idx >> 5;
        int xc = (idx & 31) << 2;
        int grow = row0 + xr;
        float4 v = make_float4(0.f, 0.f, 0.f, 0.f);
        if (grow < n) v = *(const float4*)&in[(size_t)grow * 128 + xc];
        *(float4*)&xs[xr][xc] = v;
    }

    float acc[4][4] = {};
    for (int kk = 0; kk < 128; kk += 64) {
        __syncthreads();
        #pragma unroll
        for (int i = 0; i < 8; ++i) {
            int idx = t + i * 256;
            int wr = idx >> 5;
            int wc = (idx & 31) << 2;
            *(float4*)&Ws[wr][wc] = *(const float4*)&W[(size_t)(kk + wr) * 128 + wc];
        }
        __syncthreads();
        for (int k = 0; k < 64; k += 4) {
            float4 xv0 = *(const float4*)&xs[r4 + 0][kk + k];
            float4 xv1 = *(const float4*)&xs[r4 + 1][kk + k];
            float4 xv2 = *(const float4*)&xs[r4 + 2][kk + k];
            float4 xv3 = *(const float4*)&xs[r4 + 3][kk + k];
            const float* xp0 = (const float*)&xv0;
            const float* xp1 = (const float*)&xv1;
            const float* xp2 = (const float*)&xv2;
            const float* xp3 = (const float*)&xv3;
            #pragma unroll
            for (int j = 0; j < 4; ++j) {
                float4 wv = *(const float4*)&Ws[k + j][c4];
                acc[0][0] = fmaf(xp0[j], wv.x, acc[0][0]);
                acc[0][1] = fmaf(xp0[j], wv.y, acc[0][1]);
                acc[0][2] = fmaf(xp0[j], wv.z, acc[0][2]);
                acc[0][3] = fmaf(xp0[j], wv.w, acc[0][3]);
                acc[1][0] = fmaf(xp1[j], wv.x, acc[1][0]);
                acc[1][1] = fmaf(xp1[j], wv.y, acc[1][1]);
                acc[1][2] = fmaf(xp1[j], wv.z, acc[1][2]);
                acc[1][3] = fmaf(xp1[j], wv.w, acc[1][3]);
                acc[2][0] = fmaf(xp2[j], wv.x, acc[2][0]);
                acc[2][1] = fmaf(xp2[j], wv.y, acc[2][1]);
                acc[2][2] = fmaf(xp2[j], wv.z, acc[2][2]);
                acc[2][3] = fmaf(xp2[j], wv.w, acc[2][3]);
                acc[3][0] = fmaf(xp3[j], wv.x, acc[3][0]);
                acc[3][1] = fmaf(xp3[j], wv.y, acc[3][1]);
                acc[3][2] = fmaf(xp3[j], wv.z, acc[3][2]);
                acc[3][3] = fmaf(xp3[j], wv.w, acc[3][3]);
            }
        }
    }
    #pragma unroll
    for (int i = 0; i < 4; ++i) {
        int grow = row0 + r4 + i;
        if (grow < n) {
            float ds = dis[grow];
            float4 o = make_float4(acc[i][0] * ds, acc[i][1] * ds,
                                   acc[i][2] * ds, acc[i][3] * ds);
            *(float4*)&out[(size_t)grow * 128 + c4] = o;
        }
    }
}

// ---------------- aggregation + bias + BN + ReLU ----------------
// one wave per node; lanes hold 2 features each (float2)

__global__ __launch_bounds__(256) void k_agg_bn_relu(const float* __restrict__ hws,
                                                     const int* __restrict__ row_ptr,
                                                     const int* __restrict__ col_idx,
                                                     const float* __restrict__ dis,
                                                     const float* __restrict__ bias,
                                                     const float* __restrict__ gamma,
                                                     const float* __restrict__ beta,
                                                     const float* __restrict__ mean,
                                                     const float* __restrict__ var,
                                                     float* __restrict__ out, int n) {
    int wave = threadIdx.x >> 6;
    int lane = threadIdx.x & 63;
    int d = blockIdx.x * 4 + wave;
    if (d >= n) return;
    int e0 = row_ptr[d];
    int e1 = row_ptr[d + 1];
    const float2* base = (const float2*)hws;
    float2 acc = make_float2(0.f, 0.f);
    int e = e0;
    for (; e + 4 <= e1; e += 4) {
        int s0 = col_idx[e + 0];
        int s1 = col_idx[e + 1];
        int s2 = col_idx[e + 2];
        int s3 = col_idx[e + 3];
        float2 v0 = base[(size_t)s0 * 64 + lane];
        float2 v1 = base[(size_t)s1 * 64 + lane];
        float2 v2 = base[(size_t)s2 * 64 + lane];
        float2 v3 = base[(size_t)s3 * 64 + lane];
        acc.x += v0.x + v1.x + v2.x + v3.x;
        acc.y += v0.y + v1.y + v2.y + v3.y;
    }
    for (; e < e1; ++e) {
        int s = col_idx[e];
        float2 v = base[(size_t)s * 64 + lane];
        acc.x += v.x;
        acc.y += v.y;
    }
    float2 self = base[(size_t)d * 64 + lane];
    acc.x += self.x;
    acc.y += self.y;
    float dd = dis[d];
    int f = lane * 2;
    float2 bv = *(const float2*)&bias[f];
    float2 gm = *(const float2*)&gamma[f];
    float2 bt = *(const float2*)&beta[f];
    float2 mn = *(const float2*)&mean[f];
    float2 vr = *(const float2*)&var[f];
    float vx = acc.x * dd + bv.x;
    float vy = acc.y * dd + bv.y;
    float sx = gm.x * rsqrtf(vr.x + BN_EPS);
    float sy = gm.y * rsqrtf(vr.y + BN_EPS);
    float rx = fmaxf((vx - mn.x) * sx + bt.x, 0.f);
    float ry = fmaxf((vy - mn.y) * sy + bt.y, 0.f);
    *(float2*)&out[(size_t)d * 128 + f] = make_float2(rx, ry);
}

// ---------------- attention + segment pooling ----------------

__global__ __launch_bounds__(256) void k_att_pool(const float* __restrict__ h2,
                                                  const int* __restrict__ batch,
                                                  const float* __restrict__ att_w,
                                                  float* __restrict__ att_out,
                                                  float* __restrict__ gpool, int n) {
    __shared__ float sh_att[256];
    int chunk = blockIdx.x * 256;
    int wave = threadIdx.x >> 6;
    int lane = threadIdx.x & 63;
    float2 aw = *(const float2*)&att_w[lane * 2];
    for (int rr = 0; rr < 64; ++rr) {
        int local = wave * 64 + rr;
        int row = chunk + local;
        if (row < n) {
            float2 v = *(const float2*)&h2[(size_t)row * 128 + lane * 2];
            float p = v.x * aw.x + v.y * aw.y;
            #pragma unroll
            for (int off = 32; off > 0; off >>= 1) p += __shfl_down(p, off);
            if (lane == 0) {
                float a = 1.f / (1.f + expf(-p));
                att_out[row] = a;
                sh_att[local] = a;
            }
        }
    }
    __syncthreads();
    int f = threadIdx.x & 127;
    int half = threadIdx.x >> 7;
    int r0 = half * 128, r1 = r0 + 128;
    float acc = 0.f;
    int cur = -1;
    for (int rr = r0; rr < r1; ++rr) {
        int row = chunk + rr;
        if (row >= n) break;
        int g = batch[row];
        if (g != cur) {
            if (cur >= 0) atomicAdd(&gpool[cur * 128 + f], acc);
            acc = 0.f;
            cur = g;
        }
        acc += h2[(size_t)row * 128 + f] * sh_att[rr];
    }
    if (cur >= 0) atomicAdd(&gpool[cur * 128 + f], acc);
}

__global__ __launch_bounds__(256) void k_logits(const float* __restrict__ gpool,
                                                const float* __restrict__ cls_w,
                                                const float* __restrict__ cls_b,
                                                float* __restrict__ out) {
    int wave = threadIdx.x >> 6;
    int lane = threadIdx.x & 63;
    float2 cw = *(const float2*)&cls_w[lane * 2];
    for (int g = wave; g < NG; g += 4) {
        float2 v = *(const float2*)&gpool[g * 128 + lane * 2];
        float p = v.x * cw.x + v.y * cw.y;
        #pragma unroll
        for (int off = 32; off > 0; off >>= 1) p += __shfl_down(p, off);
        if (lane == 0) out[g] = p + cls_b[0];
    }
}

// ---------------- launch ----------------

extern "C" void kernel_launch(void* const* d_in, const int* in_sizes, int n_in,
                              void* d_out, int out_size, void* d_ws, size_t ws_size,
                              hipStream_t stream) {
    const float* x   = (const float*)d_in[0];
    const int*   ei  = (const int*)d_in[1];
    const int*   bat = (const int*)d_in[2];
    const float* W1  = (const float*)d_in[3];
    const float* b1  = (const float*)d_in[4];
    const float* g1  = (const float*)d_in[5];
    const float* bt1 = (const float*)d_in[6];
    const float* mn1 = (const float*)d_in[7];
    const float* vr1 = (const float*)d_in[8];
    const float* W2  = (const float*)d_in[9];
    const float* b2  = (const float*)d_in[10];
    const float* g2  = (const float*)d_in[11];
    const float* bt2 = (const float*)d_in[12];
    const float* mn2 = (const float*)d_in[13];
    const float* vr2 = (const float*)d_in[14];
    const float* attw = (const float*)d_in[15];
    const float* clsw = (const float*)d_in[16];
    const float* clsb = (const float*)d_in[17];

    int E = in_sizes[1] / 2;
    int n = in_sizes[2];
    const int* src = ei;
    const int* dst = ei + E;

    char* ws = (char*)d_ws;
    auto alloc = [&](size_t bytes) {
        void* p = (void*)ws;
        ws += (bytes + 255) & ~(size_t)255;
        return p;
    };
    int*   ideg    = (int*)alloc((size_t)n * 4);
    int*   row_ptr = (int*)alloc((size_t)(n + 1) * 4);
    int*   bsum    = (int*)alloc(256 * 4);
    int*   col_idx = (int*)alloc((size_t)E * 4);
    float* dis     = (float*)alloc((size_t)n * 4);
    float* bufA    = (float*)alloc((size_t)n * 128 * 4);
    float* bufB    = (float*)alloc((size_t)n * 128 * 4);
    float* gpool   = (float*)alloc((size_t)NG * 128 * 4);
    // pos[] aliases bufA: consumed by k_scatter BEFORE the first GEMM writes bufA
    int*   pos     = (int*)bufA;

    hipMemsetAsync(ideg, 0, (size_t)n * 4, stream);
    hipMemsetAsync(gpool, 0, (size_t)NG * 128 * 4, stream);

    int eb  = (E + 255) / 256;
    int nbn = (n + 255) / 256;

    k_rank_deg<<<eb, 256, 0, stream>>>(dst, ideg, pos, E);
    k_dis<<<nbn, 256, 0, stream>>>(ideg, dis, n);
    k_scan_a<<<nbn, 256, 0, stream>>>(ideg, bsum, n);
    k_scan_b<<<1, 256, 0, stream>>>(bsum, nbn, row_ptr, n, E);
    k_scan_c<<<nbn, 256, 0, stream>>>(ideg, bsum, row_ptr, n);
    k_scatter<<<eb, 256, 0, stream>>>(src, dst, row_ptr, pos, col_idx, E);

    int gb = (n + 31) / 32;
    int ab = (n + 3) / 4;
    k_gemm_scale<<<gb, 256, 0, stream>>>(x, W1, dis, bufA, n);
    k_agg_bn_relu<<<ab, 256, 0, stream>>>(bufA, row_ptr, col_idx, dis, b1, g1, bt1, mn1, vr1, bufB, n);
    k_gemm_scale<<<gb, 256, 0, stream>>>(bufB, W2, dis, bufA, n);
    k_agg_bn_relu<<<ab, 256, 0, stream>>>(bufA, row_ptr, col_idx, dis, b2, g2, bt2, mn2, vr2, bufB, n);

    float* out = (float*)d_out;
    k_att_pool<<<nbn, 256, 0, stream>>>(bufB, bat, attw, out + NG, gpool, n);
    k_logits<<<1, 256, 0, stream>>>(gpool, clsw, clsb, out);
}

// Round 3
// 564.542 us; speedup vs baseline: 1.1864x; 1.0053x over previous
//
#include <hip/hip_runtime.h>
#include <math.h>

#define NN 50000
#define HID 128
#define NG 64
#define BN_EPS 1e-5f

// ---- bf16 pack/unpack (RNE) ----
__device__ inline unsigned pack_bf2(float a, float b) {
    union { float f; unsigned u; } ua, ub;
    ua.f = a; ub.f = b;
    unsigned x = ua.u, y = ub.u;
    x += 0x7fffu + ((x >> 16) & 1u);
    y += 0x7fffu + ((y >> 16) & 1u);
    return (x >> 16) | (y & 0xffff0000u);
}
__device__ inline float2 unpack_bf2(unsigned v) {
    union { unsigned u; float f; } a, b;
    a.u = v << 16;
    b.u = v & 0xffff0000u;
    return make_float2(a.f, b.f);
}

// ---------------- degree+rank / CSR build ----------------

__global__ __launch_bounds__(256) void k_rank_deg(const int* __restrict__ dst,
                                                  int* __restrict__ ideg,
                                                  int* __restrict__ pos, int E) {
    int e = blockIdx.x * 256 + threadIdx.x;
    if (e < E) pos[e] = atomicAdd(&ideg[dst[e]], 1);
}

__global__ __launch_bounds__(256) void k_dis(const int* __restrict__ ideg,
                                             float* __restrict__ dis, int n) {
    int i = blockIdx.x * 256 + threadIdx.x;
    if (i < n) dis[i] = rsqrtf((float)(ideg[i] + 1));  // +1 self-loop
}

__global__ __launch_bounds__(256) void k_scan_a(const int* __restrict__ ideg,
                                                int* __restrict__ bsum, int n) {
    __shared__ int s[256];
    int t = threadIdx.x;
    int i = blockIdx.x * 256 + t;
    s[t] = (i < n) ? ideg[i] : 0;
    __syncthreads();
    for (int off = 128; off > 0; off >>= 1) {
        if (t < off) s[t] += s[t + off];
        __syncthreads();
    }
    if (t == 0) bsum[blockIdx.x] = s[0];
}

__global__ __launch_bounds__(256) void k_scan_b(int* __restrict__ bsum, int nb,
                                                int* __restrict__ row_ptr, int n, int E) {
    __shared__ int s[256];
    int t = threadIdx.x;
    s[t] = (t < nb) ? bsum[t] : 0;
    __syncthreads();
    for (int off = 1; off < 256; off <<= 1) {
        int v = (t >= off) ? s[t - off] : 0;
        __syncthreads();
        s[t] += v;
        __syncthreads();
    }
    int ex = (t == 0) ? 0 : s[t - 1];
    if (t < nb) bsum[t] = ex;
    if (t == 0) row_ptr[n] = E;
}

__global__ __launch_bounds__(256) void k_scan_c(const int* __restrict__ ideg,
                                                const int* __restrict__ boff,
                                                int* __restrict__ row_ptr, int n) {
    __shared__ int s[256];
    int t = threadIdx.x;
    int i = blockIdx.x * 256 + t;
    int v = (i < n) ? ideg[i] : 0;
    s[t] = v;
    __syncthreads();
    for (int off = 1; off < 256; off <<= 1) {
        int u = (t >= off) ? s[t - off] : 0;
        __syncthreads();
        s[t] += u;
        __syncthreads();
    }
    int excl = s[t] - v;
    int base = boff[blockIdx.x];
    if (i < n) row_ptr[i] = base + excl;
}

__global__ __launch_bounds__(256) void k_scatter(const int* __restrict__ src,
                                                 const int* __restrict__ dst,
                                                 const int* __restrict__ row_ptr,
                                                 const int* __restrict__ pos,
                                                 int* __restrict__ col_idx, int E) {
    int e = blockIdx.x * 256 + threadIdx.x;
    if (e < E) {
        int d = dst[e];
        col_idx[row_ptr[d] + pos[e]] = src[e];
    }
}

// ---------------- GEMM: outb[row][c] = bf16( dis[row] * sum_k in[row][k]*W[k][c] ) --------

__global__ __launch_bounds__(256) void k_gemm_scale(const float* __restrict__ in,
                                                    const float* __restrict__ W,
                                                    const float* __restrict__ dis,
                                                    unsigned short* __restrict__ outb, int n) {
    __shared__ float Ws[64][128];
    __shared__ float xs[32][132];
    int t = threadIdx.x;
    int row0 = blockIdx.x * 32;
    int r4 = (t >> 5) * 4;
    int c4 = (t & 31) * 4;

    #pragma unroll
    for (int i = 0; i < 4; ++i) {
        int idx = t + i * 256;
        int xr = idx >> 5;
        int xc = (idx & 31) << 2;
        int grow = row0 + xr;
        float4 v = make_float4(0.f, 0.f, 0.f, 0.f);
        if (grow < n) v = *(const float4*)&in[(size_t)grow * 128 + xc];
        *(float4*)&xs[xr][xc] = v;
    }

    float acc[4][4] = {};
    for (int kk = 0; kk < 128; kk += 64) {
        __syncthreads();
        #pragma unroll
        for (int i = 0; i < 8; ++i) {
            int idx = t + i * 256;
            int wr = idx >> 5;
            int wc = (idx & 31) << 2;
            *(float4*)&Ws[wr][wc] = *(const float4*)&W[(size_t)(kk + wr) * 128 + wc];
        }
        __syncthreads();
        for (int k = 0; k < 64; k += 4) {
            float4 xv0 = *(const float4*)&xs[r4 + 0][kk + k];
            float4 xv1 = *(const float4*)&xs[r4 + 1][kk + k];
            float4 xv2 = *(const float4*)&xs[r4 + 2][kk + k];
            float4 xv3 = *(const float4*)&xs[r4 + 3][kk + k];
            const float* xp0 = (const float*)&xv0;
            const float* xp1 = (const float*)&xv1;
            const float* xp2 = (const float*)&xv2;
            const float* xp3 = (const float*)&xv3;
            #pragma unroll
            for (int j = 0; j < 4; ++j) {
                float4 wv = *(const float4*)&Ws[k + j][c4];
                acc[0][0] = fmaf(xp0[j], wv.x, acc[0][0]);
                acc[0][1] = fmaf(xp0[j], wv.y, acc[0][1]);
                acc[0][2] = fmaf(xp0[j], wv.z, acc[0][2]);
                acc[0][3] = fmaf(xp0[j], wv.w, acc[0][3]);
                acc[1][0] = fmaf(xp1[j], wv.x, acc[1][0]);
                acc[1][1] = fmaf(xp1[j], wv.y, acc[1][1]);
                acc[1][2] = fmaf(xp1[j], wv.z, acc[1][2]);
                acc[1][3] = fmaf(xp1[j], wv.w, acc[1][3]);
                acc[2][0] = fmaf(xp2[j], wv.x, acc[2][0]);
                acc[2][1] = fmaf(xp2[j], wv.y, acc[2][1]);
                acc[2][2] = fmaf(xp2[j], wv.z, acc[2][2]);
                acc[2][3] = fmaf(xp2[j], wv.w, acc[2][3]);
                acc[3][0] = fmaf(xp3[j], wv.x, acc[3][0]);
                acc[3][1] = fmaf(xp3[j], wv.y, acc[3][1]);
                acc[3][2] = fmaf(xp3[j], wv.z, acc[3][2]);
                acc[3][3] = fmaf(xp3[j], wv.w, acc[3][3]);
            }
        }
    }
    #pragma unroll
    for (int i = 0; i < 4; ++i) {
        int grow = row0 + r4 + i;
        if (grow < n) {
            float ds = dis[grow];
            uint2 o;
            o.x = pack_bf2(acc[i][0] * ds, acc[i][1] * ds);
            o.y = pack_bf2(acc[i][2] * ds, acc[i][3] * ds);
            *(uint2*)&outb[(size_t)grow * 128 + c4] = o;
        }
    }
}

// ---------------- aggregation + bias + BN + ReLU (bf16 gather) ----------------
// one wave per node; lane l holds features 2l,2l+1 (one packed bf16x2 = 4B per neighbor)

__global__ __launch_bounds__(256) void k_agg_bn_relu(const unsigned* __restrict__ hwsb,
                                                     const int* __restrict__ row_ptr,
                                                     const int* __restrict__ col_idx,
                                                     const float* __restrict__ dis,
                                                     const float* __restrict__ bias,
                                                     const float* __restrict__ gamma,
                                                     const float* __restrict__ beta,
                                                     const float* __restrict__ mean,
                                                     const float* __restrict__ var,
                                                     float* __restrict__ out, int n) {
    int wave = threadIdx.x >> 6;
    int lane = threadIdx.x & 63;
    int d = blockIdx.x * 4 + wave;
    if (d >= n) return;
    int e0 = row_ptr[d];
    int e1 = row_ptr[d + 1];
    float2 acc = make_float2(0.f, 0.f);
    int e = e0;
    for (; e + 8 <= e1; e += 8) {
        int s0 = col_idx[e + 0];
        int s1 = col_idx[e + 1];
        int s2 = col_idx[e + 2];
        int s3 = col_idx[e + 3];
        int s4 = col_idx[e + 4];
        int s5 = col_idx[e + 5];
        int s6 = col_idx[e + 6];
        int s7 = col_idx[e + 7];
        unsigned v0 = hwsb[(size_t)s0 * 64 + lane];
        unsigned v1 = hwsb[(size_t)s1 * 64 + lane];
        unsigned v2 = hwsb[(size_t)s2 * 64 + lane];
        unsigned v3 = hwsb[(size_t)s3 * 64 + lane];
        unsigned v4 = hwsb[(size_t)s4 * 64 + lane];
        unsigned v5 = hwsb[(size_t)s5 * 64 + lane];
        unsigned v6 = hwsb[(size_t)s6 * 64 + lane];
        unsigned v7 = hwsb[(size_t)s7 * 64 + lane];
        float2 f0 = unpack_bf2(v0), f1 = unpack_bf2(v1);
        float2 f2 = unpack_bf2(v2), f3 = unpack_bf2(v3);
        float2 f4 = unpack_bf2(v4), f5 = unpack_bf2(v5);
        float2 f6 = unpack_bf2(v6), f7 = unpack_bf2(v7);
        acc.x += (f0.x + f1.x) + (f2.x + f3.x) + (f4.x + f5.x) + (f6.x + f7.x);
        acc.y += (f0.y + f1.y) + (f2.y + f3.y) + (f4.y + f5.y) + (f6.y + f7.y);
    }
    for (; e < e1; ++e) {
        int s = col_idx[e];
        float2 f = unpack_bf2(hwsb[(size_t)s * 64 + lane]);
        acc.x += f.x;
        acc.y += f.y;
    }
    float2 self = unpack_bf2(hwsb[(size_t)d * 64 + lane]);
    acc.x += self.x;
    acc.y += self.y;
    float dd = dis[d];
    int f = lane * 2;
    float2 bv = *(const float2*)&bias[f];
    float2 gm = *(const float2*)&gamma[f];
    float2 bt = *(const float2*)&beta[f];
    float2 mn = *(const float2*)&mean[f];
    float2 vr = *(const float2*)&var[f];
    float vx = acc.x * dd + bv.x;
    float vy = acc.y * dd + bv.y;
    float sx = gm.x * rsqrtf(vr.x + BN_EPS);
    float sy = gm.y * rsqrtf(vr.y + BN_EPS);
    float rx = fmaxf((vx - mn.x) * sx + bt.x, 0.f);
    float ry = fmaxf((vy - mn.y) * sy + bt.y, 0.f);
    *(float2*)&out[(size_t)d * 128 + f] = make_float2(rx, ry);
}

// ---------------- attention + segment pooling ----------------

__global__ __launch_bounds__(256) void k_att_pool(const float* __restrict__ h2,
                                                  const int* __restrict__ batch,
                                                  const float* __restrict__ att_w,
                                                  float* __restrict__ att_out,
                                                  float* __restrict__ gpool, int n) {
    __shared__ float sh_att[256];
    int chunk = blockIdx.x * 256;
    int wave = threadIdx.x >> 6;
    int lane = threadIdx.x & 63;
    float2 aw = *(const float2*)&att_w[lane * 2];
    for (int rr = 0; rr < 64; ++rr) {
        int local = wave * 64 + rr;
        int row = chunk + local;
        if (row < n) {
            float2 v = *(const float2*)&h2[(size_t)row * 128 + lane * 2];
            float p = v.x * aw.x + v.y * aw.y;
            #pragma unroll
            for (int off = 32; off > 0; off >>= 1) p += __shfl_down(p, off);
            if (lane == 0) {
                float a = 1.f / (1.f + expf(-p));
                att_out[row] = a;
                sh_att[local] = a;
            }
        }
    }
    __syncthreads();
    int f = threadIdx.x & 127;
    int half = threadIdx.x >> 7;
    int r0 = half * 128, r1 = r0 + 128;
    float acc = 0.f;
    int cur = -1;
    for (int rr = r0; rr < r1; ++rr) {
        int row = chunk + rr;
        if (row >= n) break;
        int g = batch[row];
        if (g != cur) {
            if (cur >= 0) atomicAdd(&gpool[cur * 128 + f], acc);
            acc = 0.f;
            cur = g;
        }
        acc += h2[(size_t)row * 128 + f] * sh_att[rr];
    }
    if (cur >= 0) atomicAdd(&gpool[cur * 128 + f], acc);
}

__global__ __launch_bounds__(256) void k_logits(const float* __restrict__ gpool,
                                                const float* __restrict__ cls_w,
                                                const float* __restrict__ cls_b,
                                                float* __restrict__ out) {
    int wave = threadIdx.x >> 6;
    int lane = threadIdx.x & 63;
    float2 cw = *(const float2*)&cls_w[lane * 2];
    for (int g = wave; g < NG; g += 4) {
        float2 v = *(const float2*)&gpool[g * 128 + lane * 2];
        float p = v.x * cw.x + v.y * cw.y;
        #pragma unroll
        for (int off = 32; off > 0; off >>= 1) p += __shfl_down(p, off);
        if (lane == 0) out[g] = p + cls_b[0];
    }
}

// ---------------- launch ----------------

extern "C" void kernel_launch(void* const* d_in, const int* in_sizes, int n_in,
                              void* d_out, int out_size, void* d_ws, size_t ws_size,
                              hipStream_t stream) {
    const float* x   = (const float*)d_in[0];
    const int*   ei  = (const int*)d_in[1];
    const int*   bat = (const int*)d_in[2];
    const float* W1  = (const float*)d_in[3];
    const float* b1  = (const float*)d_in[4];
    const float* g1  = (const float*)d_in[5];
    const float* bt1 = (const float*)d_in[6];
    const float* mn1 = (const float*)d_in[7];
    const float* vr1 = (const float*)d_in[8];
    const float* W2  = (const float*)d_in[9];
    const float* b2  = (const float*)d_in[10];
    const float* g2  = (const float*)d_in[11];
    const float* bt2 = (const float*)d_in[12];
    const float* mn2 = (const float*)d_in[13];
    const float* vr2 = (const float*)d_in[14];
    const float* attw = (const float*)d_in[15];
    const float* clsw = (const float*)d_in[16];
    const float* clsb = (const float*)d_in[17];

    int E = in_sizes[1] / 2;
    int n = in_sizes[2];
    const int* src = ei;
    const int* dst = ei + E;

    char* ws = (char*)d_ws;
    auto alloc = [&](size_t bytes) {
        void* p = (void*)ws;
        ws += (bytes + 255) & ~(size_t)255;
        return p;
    };
    int*            ideg    = (int*)alloc((size_t)n * 4);
    int*            row_ptr = (int*)alloc((size_t)(n + 1) * 4);
    int*            bsum    = (int*)alloc(256 * 4);
    int*            col_idx = (int*)alloc((size_t)E * 4);
    float*          dis     = (float*)alloc((size_t)n * 4);
    unsigned short* hwsb    = (unsigned short*)alloc((size_t)n * 128 * 2);  // bf16 staging
    float*          bufB    = (float*)alloc((size_t)n * 128 * 4);           // h1 / h2 (f32)
    float*          gpool   = (float*)alloc((size_t)NG * 128 * 4);
    int*            pos     = (int*)alloc((size_t)E * 4);

    hipMemsetAsync(ideg, 0, (size_t)n * 4, stream);
    hipMemsetAsync(gpool, 0, (size_t)NG * 128 * 4, stream);

    int eb  = (E + 255) / 256;
    int nbn = (n + 255) / 256;

    k_rank_deg<<<eb, 256, 0, stream>>>(dst, ideg, pos, E);
    k_dis<<<nbn, 256, 0, stream>>>(ideg, dis, n);
    k_scan_a<<<nbn, 256, 0, stream>>>(ideg, bsum, n);
    k_scan_b<<<1, 256, 0, stream>>>(bsum, nbn, row_ptr, n, E);
    k_scan_c<<<nbn, 256, 0, stream>>>(ideg, bsum, row_ptr, n);
    k_scatter<<<eb, 256, 0, stream>>>(src, dst, row_ptr, pos, col_idx, E);

    int gb = (n + 31) / 32;
    int ab = (n + 3) / 4;
    k_gemm_scale<<<gb, 256, 0, stream>>>(x, W1, dis, hwsb, n);
    k_agg_bn_relu<<<ab, 256, 0, stream>>>((const unsigned*)hwsb, row_ptr, col_idx, dis,
                                          b1, g1, bt1, mn1, vr1, bufB, n);
    k_gemm_scale<<<gb, 256, 0, stream>>>(bufB, W2, dis, hwsb, n);
    k_agg_bn_relu<<<ab, 256, 0, stream>>>((const unsigned*)hwsb, row_ptr, col_idx, dis,
                                          b2, g2, bt2, mn2, vr2, bufB, n);

    float* out = (float*)d_out;
    k_att_pool<<<nbn, 256, 0, stream>>>(bufB, bat, attw, out + NG, gpool, n);
    k_logits<<<1, 256, 0, stream>>>(gpool, clsw, clsb, out);
}